// Round 2
// baseline (576.183 us; speedup 1.0000x reference)
//
#include <hip/hip_runtime.h>
#include <stdint.h>

#define T_TOK 4096
#define H_DIM 1024
#define E_EXP 8
#define DFF_D 4096
#define HROWS 9216
#define NTILE_MAX 72

typedef __attribute__((ext_vector_type(4))) float f32x4;
typedef __attribute__((ext_vector_type(8))) __bf16 bf16x8;

static __device__ __forceinline__ unsigned short f2bf(float f) {
  union { float f; unsigned u; } v; v.f = f;
  unsigned r = v.u + 0x7FFFu + ((v.u >> 16) & 1u);
  return (unsigned short)(r >> 16);
}
static __device__ __forceinline__ float bf2f(unsigned short u) {
  union { unsigned u; float f; } v; v.u = ((unsigned)u) << 16; return v.f;
}
static __device__ __forceinline__ void load_lds16(const void* g, void* l) {
  __builtin_amdgcn_global_load_lds(
      (const __attribute__((address_space(1))) unsigned int*)g,
      (__attribute__((address_space(3))) unsigned int*)l, 16, 0, 0);
}

// ---------------- x -> bf16 ----------------
__global__ void cvt_x_kernel(const float* __restrict__ x, unsigned short* __restrict__ xb) {
  const int i = blockIdx.x * 256 + threadIdx.x;
  const float4* xv = (const float4*)x;
  float4 a = xv[(size_t)i * 2], b = xv[(size_t)i * 2 + 1];
  ushort4 o0, o1;
  o0.x = f2bf(a.x); o0.y = f2bf(a.y); o0.z = f2bf(a.z); o0.w = f2bf(a.w);
  o1.x = f2bf(b.x); o1.y = f2bf(b.y); o1.z = f2bf(b.z); o1.w = f2bf(b.w);
  *(ushort4*)&xb[(size_t)i * 8]     = o0;
  *(ushort4*)&xb[(size_t)i * 8 + 4] = o1;
}

// ---------------- transpose+convert, 64x64 tile, float4 loads / 16B stores ----------------
// dst[c][r] = bf16(src[r][c]); src [R][C] f32 per expert (blockIdx.z)
__global__ __launch_bounds__(256) void tr_cvt_kernel(const float* __restrict__ src0,
                                                     unsigned short* __restrict__ dst0,
                                                     int R, int C) {
  __shared__ float tile[64][68];
  const size_t eo = (size_t)blockIdx.z * R * C;
  const float* src = src0 + eo;
  unsigned short* dst = dst0 + eo;
  const int r0 = blockIdx.y * 64, c0 = blockIdx.x * 64;
  const int tid = threadIdx.x;
  const int lr = tid >> 4, lc4 = tid & 15;
#pragma unroll
  for (int j = 0; j < 4; ++j) {
    int r = lr + j * 16;
    float4 v = *(const float4*)&src[(size_t)(r0 + r) * C + c0 + lc4 * 4];
    *(float4*)&tile[r][lc4 * 4] = v;
  }
  __syncthreads();
  const int c = tid >> 2, rb = (tid & 3) * 16;
  unsigned outw[8];
#pragma unroll
  for (int k = 0; k < 8; ++k) {
    unsigned short lo = f2bf(tile[rb + 2 * k][c]);
    unsigned short hi = f2bf(tile[rb + 2 * k + 1][c]);
    outw[k] = (unsigned)lo | ((unsigned)hi << 16);
  }
  unsigned short* dp = &dst[(size_t)(c0 + c) * R + r0 + rb];
  *(uint4*)(dp)     = *(uint4*)&outw[0];
  *(uint4*)(dp + 8) = *(uint4*)&outw[4];
}

// ---------------- gate: logits, softmax, top-2, scatter, aux partials ----------------
__global__ void gate_kernel(const float* __restrict__ x, const float* __restrict__ gw,
                            const float* __restrict__ gb,
                            int* __restrict__ counts,
                            int* __restrict__ entry_token, float* __restrict__ entry_gate,
                            int* __restrict__ ids, int* __restrict__ slots,
                            float* __restrict__ partials) {
  __shared__ float probs_lds[4][8];
  __shared__ int   topi_lds[4][2];
  const int tid = threadIdx.x;
  const int lane = tid & 63, tl = tid >> 6;
  const int token = blockIdx.x * 4 + tl;
  float a[8];
#pragma unroll
  for (int e = 0; e < 8; ++e) a[e] = 0.f;
#pragma unroll
  for (int i = 0; i < 16; ++i) {
    int k = i * 64 + lane;
    float xv = x[(size_t)token * H_DIM + k];
    const float4* g = (const float4*)&gw[(size_t)k * 8];
    float4 g0 = g[0], g1 = g[1];
    a[0] += xv * g0.x; a[1] += xv * g0.y; a[2] += xv * g0.z; a[3] += xv * g0.w;
    a[4] += xv * g1.x; a[5] += xv * g1.y; a[6] += xv * g1.z; a[7] += xv * g1.w;
  }
  for (int m = 32; m >= 1; m >>= 1) {
#pragma unroll
    for (int e = 0; e < 8; ++e) a[e] += __shfl_xor(a[e], m);
  }
  if (lane == 0) {
    float lg[8], p[8];
    float mx = -1e30f;
#pragma unroll
    for (int e = 0; e < 8; ++e) { lg[e] = a[e] + gb[e]; mx = lg[e] > mx ? lg[e] : mx; }
    float s = 0.f;
#pragma unroll
    for (int e = 0; e < 8; ++e) { p[e] = expf(lg[e] - mx); s += p[e]; }
    float inv = 1.f / s;
#pragma unroll
    for (int e = 0; e < 8; ++e) p[e] *= inv;
    int i0 = 0;
#pragma unroll
    for (int e = 1; e < 8; ++e) if (p[e] > p[i0]) i0 = e;
    int i1 = (i0 == 0) ? 1 : 0;
#pragma unroll
    for (int e = 0; e < 8; ++e) if (e != i0 && p[e] > p[i1]) i1 = e;
#pragma unroll
    for (int e = 0; e < 8; ++e) probs_lds[tl][e] = p[e];
    topi_lds[tl][0] = i0; topi_lds[tl][1] = i1;
    int s0 = atomicAdd(&counts[i0], 1);
    entry_token[i0 * T_TOK + s0] = token;
    entry_gate[i0 * T_TOK + s0] = p[i0];
    ids[token * 2] = i0; slots[token * 2] = s0;
    int s1 = atomicAdd(&counts[i1], 1);
    entry_token[i1 * T_TOK + s1] = token;
    entry_gate[i1 * T_TOK + s1] = p[i1];
    ids[token * 2 + 1] = i1; slots[token * 2 + 1] = s1;
  }
  __syncthreads();
  if (tid < 24) {
    int e = tid & 7, which = tid >> 3;
    float s = 0.f;
#pragma unroll
    for (int tt = 0; tt < 4; ++tt) {
      float pv = probs_lds[tt][e];
      bool m = (topi_lds[tt][0] == e) || (topi_lds[tt][1] == e);
      if (which == 0) s += pv;
      else if (which == 1) s += m ? 1.f : 0.f;
      else s += m ? pv : 0.f;
    }
    partials[blockIdx.x * 24 + tid] = s;
  }
}

// ---------------- offsets + tile map ----------------
__global__ void offsets_kernel(const int* __restrict__ counts, int* __restrict__ hoff,
                               int* __restrict__ tmap) {
  if (threadIdx.x == 0 && blockIdx.x == 0) {
    int o = 0, nt = 0;
    for (int e = 0; e < E_EXP; ++e) {
      hoff[e] = o;
      int rtc = (counts[e] + 127) >> 7;
      o += rtc << 7;
      for (int rt = 0; rt < rtc; ++rt) tmap[nt++] = (e << 16) | rt;
    }
    hoff[E_EXP] = o;
    for (; nt < NTILE_MAX; ++nt) tmap[nt] = -1;
  }
}

// ---------------- aux loss (parallel reduce) ----------------
__global__ void aux_kernel(const float* __restrict__ partials, float* __restrict__ out_aux) {
  __shared__ float red[24][33];
  const int tid = threadIdx.x;              // 1024 threads
  const int c = tid & 31, g = tid >> 5;     // g in [0,32)
  if (c < 24) {
    float s = 0.f;
    for (int j = 0; j < 32; ++j) s += partials[(size_t)(g + j * 32) * 24 + c];
    red[c][g] = s;
  }
  __syncthreads();
  if (tid < 24) {
    float t2 = 0.f;
#pragma unroll
    for (int g2 = 0; g2 < 32; ++g2) t2 += red[tid][g2];
    red[tid][32] = t2;
  }
  __syncthreads();
  if (tid == 0) {
    float mean = 0.f;
    for (int e = 0; e < 8; ++e) mean += red[e][32];
    mean *= 0.125f;
    float var = 0.f;
    for (int e = 0; e < 8; ++e) { float d = red[e][32] - mean; var += d * d; }
    var *= (1.f / 7.f);
    float il = var * (1.f / 64.f);
    float lb = 0.f;
    for (int e = 0; e < 8; ++e)
      lb += (red[8 + e][32] / (float)T_TOK) * (red[16 + e][32] / (float)T_TOK);
    lb *= 8.f;
    out_aux[0] = il + lb;
  }
}

// ---------------- GEMM1: h = relu(gather(x) @ w1[e] + b1[e]) ----------------
// 128x128 tile, BK=64, double-buffered LDS (one barrier / K-step), XCD swizzle.
__global__ __launch_bounds__(256, 2) void gemm1_kernel(
    const unsigned short* __restrict__ xb,    // [T][1024]
    const unsigned short* __restrict__ w1t,   // [E][4096][1024]
    const float* __restrict__ b1,             // [E][4096]
    const int* __restrict__ counts, const int* __restrict__ hoff,
    const int* __restrict__ tmap,
    const int* __restrict__ entry_token,
    unsigned short* __restrict__ h)           // [HROWS][4096]
{
  int lin = blockIdx.y * 32 + blockIdx.x;               // nwg = 72*32 = 2304
  lin = (lin & 7) * ((NTILE_MAX * 32) >> 3) + (lin >> 3);
  const int ct = lin & 31, ti = lin >> 5;
  const int mEnc = tmap[ti];
  if (mEnc < 0) return;
  const int e = mEnc >> 16, rt = mEnc & 0xffff;
  const int cnt = counts[e];
  __shared__ __align__(16) unsigned short As[2][128 * 64];
  __shared__ __align__(16) unsigned short Bs[2][128 * 64];
  __shared__ int tok[128];
  const int tid = threadIdx.x, lane = tid & 63, wv = tid >> 6;
  if (tid < 128) {
    int s = rt * 128 + tid;
    if (s >= cnt) s = cnt - 1;
    tok[tid] = entry_token[e * T_TOK + s];
  }
  __syncthreads();
  const unsigned short* bsrc0 = w1t + (size_t)e * DFF_D * H_DIM + (size_t)ct * 128 * H_DIM;
  const unsigned short* asrc[4]; const unsigned short* bsrc[4];
  int ldso[4];
#pragma unroll
  for (int i = 0; i < 4; ++i) {
    int cc = tid + i * 256;
    asrc[i] = xb + (size_t)tok[cc >> 3] * H_DIM + (cc & 7) * 8;
    bsrc[i] = bsrc0 + (size_t)(cc >> 3) * H_DIM + (cc & 7) * 8;
    ldso[i] = (wv * 64 + i * 256) * 8;
  }
  f32x4 acc[4][4];
#pragma unroll
  for (int mi = 0; mi < 4; ++mi)
#pragma unroll
    for (int ni = 0; ni < 4; ++ni) acc[mi][ni] = (f32x4){0.f, 0.f, 0.f, 0.f};
  const int wm = (wv >> 1) * 64, wn = (wv & 1) * 64;
#pragma unroll
  for (int i = 0; i < 4; ++i) {                          // prologue: tile 0 -> buf 0
    load_lds16(asrc[i], &As[0][ldso[i]]);
    load_lds16(bsrc[i], &Bs[0][ldso[i]]);
  }
  __syncthreads();
  for (int kt = 0; kt < 16; ++kt) {
    const int cur = kt & 1;
    if (kt + 1 < 16) {
      const int k0 = (kt + 1) * 64;
#pragma unroll
      for (int i = 0; i < 4; ++i) {                      // prefetch next tile
        load_lds16(asrc[i] + k0, &As[cur ^ 1][ldso[i]]);
        load_lds16(bsrc[i] + k0, &Bs[cur ^ 1][ldso[i]]);
      }
    }
#pragma unroll
    for (int kk = 0; kk < 2; ++kk) {
      bf16x8 af[4], bfr[4];
#pragma unroll
      for (int mi = 0; mi < 4; ++mi)
        af[mi] = *(const bf16x8*)&As[cur][(wm + mi * 16 + (lane & 15)) * 64 + kk * 32 + (lane >> 4) * 8];
#pragma unroll
      for (int ni = 0; ni < 4; ++ni)
        bfr[ni] = *(const bf16x8*)&Bs[cur][(wn + ni * 16 + (lane & 15)) * 64 + kk * 32 + (lane >> 4) * 8];
#pragma unroll
      for (int mi = 0; mi < 4; ++mi)
#pragma unroll
        for (int ni = 0; ni < 4; ++ni)
          acc[mi][ni] = __builtin_amdgcn_mfma_f32_16x16x32_bf16(af[mi], bfr[ni], acc[mi][ni], 0, 0, 0);
    }
    __syncthreads();
  }
  const int rb = hoff[e] + rt * 128;
#pragma unroll
  for (int mi = 0; mi < 4; ++mi)
#pragma unroll
    for (int ni = 0; ni < 4; ++ni) {
      const int n = ct * 128 + wn + ni * 16 + (lane & 15);
      const float bias = b1[e * DFF_D + n];
#pragma unroll
      for (int q = 0; q < 4; ++q) {
        const int m = wm + mi * 16 + (lane >> 4) * 4 + q;
        float v = acc[mi][ni][q] + bias;
        v = v > 0.f ? v : 0.f;
        h[(size_t)(rb + m) * DFF_D + n] = f2bf(v);
      }
    }
}

// ---------------- GEMM2: yp[kp] = gate * (h @ w2[e] + b2[e]) , split-K=2 ----------------
__global__ __launch_bounds__(256, 2) void gemm2_kernel(
    const unsigned short* __restrict__ h,     // [HROWS][4096]
    const unsigned short* __restrict__ w2t,   // [E][1024][4096]
    const float* __restrict__ b2,             // [E][1024]
    const int* __restrict__ counts, const int* __restrict__ hoff,
    const int* __restrict__ tmap,
    const float* __restrict__ entry_gate,
    unsigned short* __restrict__ yp)          // [2][HROWS][1024]
{
  int lin = (blockIdx.z * NTILE_MAX + blockIdx.y) * 8 + blockIdx.x;  // nwg = 2*72*8 = 1152
  lin = (lin & 7) * ((2 * NTILE_MAX * 8) >> 3) + (lin >> 3);
  const int ct = lin & 7;
  const int rest = lin >> 3;
  const int ti = rest % NTILE_MAX, kp = rest / NTILE_MAX;
  const int mEnc = tmap[ti];
  if (mEnc < 0) return;
  const int e = mEnc >> 16, rt = mEnc & 0xffff;
  __shared__ __align__(16) unsigned short As[2][128 * 64];
  __shared__ __align__(16) unsigned short Bs[2][128 * 64];
  const int tid = threadIdx.x, lane = tid & 63, wv = tid >> 6;
  const int rb = hoff[e] + rt * 128;
  const unsigned short* asrc0 = h + (size_t)rb * DFF_D + kp * 2048;
  const unsigned short* bsrc0 = w2t + (size_t)e * H_DIM * DFF_D + (size_t)ct * 128 * DFF_D + kp * 2048;
  const unsigned short* asrc[4]; const unsigned short* bsrc[4];
  int ldso[4];
#pragma unroll
  for (int i = 0; i < 4; ++i) {
    int cc = tid + i * 256;
    asrc[i] = asrc0 + (size_t)(cc >> 3) * DFF_D + (cc & 7) * 8;
    bsrc[i] = bsrc0 + (size_t)(cc >> 3) * DFF_D + (cc & 7) * 8;
    ldso[i] = (wv * 64 + i * 256) * 8;
  }
  f32x4 acc[4][4];
#pragma unroll
  for (int mi = 0; mi < 4; ++mi)
#pragma unroll
    for (int ni = 0; ni < 4; ++ni) acc[mi][ni] = (f32x4){0.f, 0.f, 0.f, 0.f};
  const int wm = (wv >> 1) * 64, wn = (wv & 1) * 64;
#pragma unroll
  for (int i = 0; i < 4; ++i) {
    load_lds16(asrc[i], &As[0][ldso[i]]);
    load_lds16(bsrc[i], &Bs[0][ldso[i]]);
  }
  __syncthreads();
  for (int kt = 0; kt < 32; ++kt) {
    const int cur = kt & 1;
    if (kt + 1 < 32) {
      const int k0 = (kt + 1) * 64;
#pragma unroll
      for (int i = 0; i < 4; ++i) {
        load_lds16(asrc[i] + k0, &As[cur ^ 1][ldso[i]]);
        load_lds16(bsrc[i] + k0, &Bs[cur ^ 1][ldso[i]]);
      }
    }
#pragma unroll
    for (int kk = 0; kk < 2; ++kk) {
      bf16x8 af[4], bfr[4];
#pragma unroll
      for (int mi = 0; mi < 4; ++mi)
        af[mi] = *(const bf16x8*)&As[cur][(wm + mi * 16 + (lane & 15)) * 64 + kk * 32 + (lane >> 4) * 8];
#pragma unroll
      for (int ni = 0; ni < 4; ++ni)
        bfr[ni] = *(const bf16x8*)&Bs[cur][(wn + ni * 16 + (lane & 15)) * 64 + kk * 32 + (lane >> 4) * 8];
#pragma unroll
      for (int mi = 0; mi < 4; ++mi)
#pragma unroll
        for (int ni = 0; ni < 4; ++ni)
          acc[mi][ni] = __builtin_amdgcn_mfma_f32_16x16x32_bf16(af[mi], bfr[ni], acc[mi][ni], 0, 0, 0);
    }
    __syncthreads();
  }
  unsigned short* yout = yp + (size_t)kp * HROWS * H_DIM;
#pragma unroll
  for (int mi = 0; mi < 4; ++mi)
#pragma unroll
    for (int ni = 0; ni < 4; ++ni) {
      const int n = ct * 128 + wn + ni * 16 + (lane & 15);
      const float bias = (kp == 0) ? b2[e * H_DIM + n] : 0.f;
#pragma unroll
      for (int q = 0; q < 4; ++q) {
        const int m = wm + mi * 16 + (lane >> 4) * 4 + q;
        const float gate = entry_gate[e * T_TOK + rt * 128 + m];  // garbage on pad rows: never read
        float v = (acc[mi][ni][q] + bias) * gate;
        yout[(size_t)(rb + m) * H_DIM + n] = f2bf(v);
      }
    }
}

// ---------------- combine: out[t] = sum_kp yp[kp][row(t,0)] + yp[kp][row(t,1)] ----------------
__global__ void combine_kernel(const unsigned short* __restrict__ yp,
                               const int* __restrict__ ids, const int* __restrict__ slots,
                               const int* __restrict__ hoff, float* __restrict__ out) {
  const int t = blockIdx.x, tid = threadIdx.x;
  const int r0 = hoff[ids[t * 2]] + slots[t * 2];
  const int r1 = hoff[ids[t * 2 + 1]] + slots[t * 2 + 1];
  const int c = tid * 4;
  float4 o = {0.f, 0.f, 0.f, 0.f};
#pragma unroll
  for (int k = 0; k < 2; ++k) {
    const unsigned short* pl = yp + (size_t)k * HROWS * H_DIM;
    ushort4 a = *(const ushort4*)&pl[(size_t)r0 * H_DIM + c];
    ushort4 b = *(const ushort4*)&pl[(size_t)r1 * H_DIM + c];
    o.x += bf2f(a.x) + bf2f(b.x);
    o.y += bf2f(a.y) + bf2f(b.y);
    o.z += bf2f(a.z) + bf2f(b.z);
    o.w += bf2f(a.w) + bf2f(b.w);
  }
  *(float4*)&out[(size_t)t * H_DIM + c] = o;
}

__global__ void ws_fail_kernel(float* out) {
  if (threadIdx.x == 0 && blockIdx.x == 0) out[0] = -12345.0f;
}

// ---------------- workspace layout (bytes) ----------------
// yp[2] planes alias xb+w1t (dead after gemm1): [0, 37,748,736)
#define XB_OFF    ((size_t)0)                 // 8,388,608 (dead after gemm1)
#define W1T_OFF   ((size_t)8388608)           // 67,108,864 (dead after gemm1)
#define YP_OFF    ((size_t)0)                 // 2 * 18,874,368 = 37,748,736
#define W2T_OFF   ((size_t)75497472)          // 67,108,864
#define H_OFF     ((size_t)142606336)         // 75,497,472
#define TMAP_OFF  ((size_t)218103808)         // 288 (old y region)
#define ET_OFF    ((size_t)236978176)         // 131,072
#define EG_OFF    ((size_t)237109248)         // 131,072
#define IDS_OFF   ((size_t)237240320)         // 32,768
#define SLOT_OFF  ((size_t)237273088)         // 32,768
#define CNT_OFF   ((size_t)237305856)         // 64
#define HOFF_OFF  ((size_t)237305920)         // 64
#define PART_OFF  ((size_t)237305984)         // 98,304
#define WS_NEED   ((size_t)237404288)

extern "C" void kernel_launch(void* const* d_in, const int* in_sizes, int n_in,
                              void* d_out, int out_size, void* d_ws, size_t ws_size,
                              hipStream_t stream) {
  const float* x  = (const float*)d_in[0];
  const float* gw = (const float*)d_in[1];
  const float* gb = (const float*)d_in[2];
  const float* w1 = (const float*)d_in[3];
  const float* b1 = (const float*)d_in[4];
  const float* w2 = (const float*)d_in[5];
  const float* b2 = (const float*)d_in[6];
  float* out = (float*)d_out;
  char* ws = (char*)d_ws;

  if (ws_size < WS_NEED) {
    ws_fail_kernel<<<1, 64, 0, stream>>>(out);
    return;
  }

  unsigned short* xb  = (unsigned short*)(ws + XB_OFF);
  unsigned short* w1t = (unsigned short*)(ws + W1T_OFF);
  unsigned short* yp  = (unsigned short*)(ws + YP_OFF);
  unsigned short* w2t = (unsigned short*)(ws + W2T_OFF);
  unsigned short* h   = (unsigned short*)(ws + H_OFF);
  int*   tmap  = (int*)(ws + TMAP_OFF);
  int*   etok  = (int*)(ws + ET_OFF);
  float* egate = (float*)(ws + EG_OFF);
  int*   ids   = (int*)(ws + IDS_OFF);
  int*   slots = (int*)(ws + SLOT_OFF);
  int*   counts= (int*)(ws + CNT_OFF);
  int*   hoff  = (int*)(ws + HOFF_OFF);
  float* parts = (float*)(ws + PART_OFF);

  hipMemsetAsync(counts, 0, 32, stream);

  cvt_x_kernel<<<2048, 256, 0, stream>>>(x, xb);
  tr_cvt_kernel<<<dim3(64, 16, 8), 256, 0, stream>>>(w1, w1t, H_DIM, DFF_D);
  tr_cvt_kernel<<<dim3(16, 64, 8), 256, 0, stream>>>(w2, w2t, DFF_D, H_DIM);
  gate_kernel<<<1024, 256, 0, stream>>>(x, gw, gb, counts, etok, egate, ids, slots, parts);
  offsets_kernel<<<1, 64, 0, stream>>>(counts, hoff, tmap);
  aux_kernel<<<1, 1024, 0, stream>>>(parts, out + (size_t)T_TOK * H_DIM);
  gemm1_kernel<<<dim3(32, NTILE_MAX), 256, 0, stream>>>(xb, w1t, b1, counts, hoff, tmap, etok, h);
  gemm2_kernel<<<dim3(8, NTILE_MAX, 2), 256, 0, stream>>>(h, w2t, b2, counts, hoff, tmap, egate, yp);
  combine_kernel<<<4096, 256, 0, stream>>>(yp, ids, slots, hoff, out);
}

// Round 3
// 398.692 us; speedup vs baseline: 1.4452x; 1.4452x over previous
//
#include <hip/hip_runtime.h>
#include <stdint.h>

#define T_TOK 4096
#define H_DIM 1024
#define E_EXP 8
#define DFF_D 4096
#define HROWS 10240
#define NT 40

typedef __attribute__((ext_vector_type(4))) float f32x4;
typedef __attribute__((ext_vector_type(8))) __bf16 bf16x8;

static __device__ __forceinline__ unsigned short f2bf(float f) {
  union { float f; unsigned u; } v; v.f = f;
  unsigned r = v.u + 0x7FFFu + ((v.u >> 16) & 1u);
  return (unsigned short)(r >> 16);
}
static __device__ __forceinline__ float bf2f(unsigned short u) {
  union { unsigned u; float f; } v; v.u = ((unsigned)u) << 16; return v.f;
}
static __device__ __forceinline__ void load_lds16(const void* g, void* l) {
  __builtin_amdgcn_global_load_lds(
      (const __attribute__((address_space(1))) unsigned int*)g,
      (__attribute__((address_space(3))) unsigned int*)l, 16, 0, 0);
}

#define MEMF() asm volatile("" ::: "memory")
#define BAR()  { MEMF(); __builtin_amdgcn_s_barrier(); MEMF(); }
#define VM2()  asm volatile("s_waitcnt vmcnt(2)" ::: "memory")
#define VM0()  asm volatile("s_waitcnt vmcnt(0)" ::: "memory")

// ---------------- x -> bf16 ----------------
__global__ void cvt_x_kernel(const float* __restrict__ x, unsigned short* __restrict__ xb) {
  const int i = blockIdx.x * 256 + threadIdx.x;
  const float4* xv = (const float4*)x;
  float4 a = xv[(size_t)i * 2], b = xv[(size_t)i * 2 + 1];
  ushort4 o0, o1;
  o0.x = f2bf(a.x); o0.y = f2bf(a.y); o0.z = f2bf(a.z); o0.w = f2bf(a.w);
  o1.x = f2bf(b.x); o1.y = f2bf(b.y); o1.z = f2bf(b.z); o1.w = f2bf(b.w);
  *(ushort4*)&xb[(size_t)i * 8]     = o0;
  *(ushort4*)&xb[(size_t)i * 8 + 4] = o1;
}

// ---------------- transpose+convert: dst[c][r] = bf16(src[r][c]) ----------------
__global__ __launch_bounds__(256) void tr_cvt_kernel(const float* __restrict__ src0,
                                                     unsigned short* __restrict__ dst0,
                                                     int R, int C) {
  __shared__ float tile[64][68];
  const size_t eo = (size_t)blockIdx.z * R * C;
  const float* src = src0 + eo;
  unsigned short* dst = dst0 + eo;
  const int r0 = blockIdx.y * 64, c0 = blockIdx.x * 64;
  const int tid = threadIdx.x;
  const int lr = tid >> 4, lc4 = tid & 15;
#pragma unroll
  for (int j = 0; j < 4; ++j) {
    int r = lr + j * 16;
    float4 v = *(const float4*)&src[(size_t)(r0 + r) * C + c0 + lc4 * 4];
    *(float4*)&tile[r][lc4 * 4] = v;
  }
  __syncthreads();
  const int c = tid >> 2, rb = (tid & 3) * 16;
  unsigned outw[8];
#pragma unroll
  for (int k = 0; k < 8; ++k) {
    unsigned short lo = f2bf(tile[rb + 2 * k][c]);
    unsigned short hi = f2bf(tile[rb + 2 * k + 1][c]);
    outw[k] = (unsigned)lo | ((unsigned)hi << 16);
  }
  unsigned short* dp = &dst[(size_t)(c0 + c) * R + r0 + rb];
  *(uint4*)(dp)     = *(uint4*)&outw[0];
  *(uint4*)(dp + 8) = *(uint4*)&outw[4];
}

// ---------------- gate ----------------
__global__ void gate_kernel(const float* __restrict__ x, const float* __restrict__ gw,
                            const float* __restrict__ gb,
                            int* __restrict__ counts,
                            int* __restrict__ entry_token, float* __restrict__ entry_gate,
                            int* __restrict__ ids, int* __restrict__ slots,
                            float* __restrict__ partials) {
  __shared__ float probs_lds[4][8];
  __shared__ int   topi_lds[4][2];
  const int tid = threadIdx.x;
  const int lane = tid & 63, tl = tid >> 6;
  const int token = blockIdx.x * 4 + tl;
  float a[8];
#pragma unroll
  for (int e = 0; e < 8; ++e) a[e] = 0.f;
#pragma unroll
  for (int i = 0; i < 16; ++i) {
    int k = i * 64 + lane;
    float xv = x[(size_t)token * H_DIM + k];
    const float4* g = (const float4*)&gw[(size_t)k * 8];
    float4 g0 = g[0], g1 = g[1];
    a[0] += xv * g0.x; a[1] += xv * g0.y; a[2] += xv * g0.z; a[3] += xv * g0.w;
    a[4] += xv * g1.x; a[5] += xv * g1.y; a[6] += xv * g1.z; a[7] += xv * g1.w;
  }
  for (int m = 32; m >= 1; m >>= 1) {
#pragma unroll
    for (int e = 0; e < 8; ++e) a[e] += __shfl_xor(a[e], m);
  }
  if (lane == 0) {
    float lg[8], p[8];
    float mx = -1e30f;
#pragma unroll
    for (int e = 0; e < 8; ++e) { lg[e] = a[e] + gb[e]; mx = lg[e] > mx ? lg[e] : mx; }
    float s = 0.f;
#pragma unroll
    for (int e = 0; e < 8; ++e) { p[e] = expf(lg[e] - mx); s += p[e]; }
    float inv = 1.f / s;
#pragma unroll
    for (int e = 0; e < 8; ++e) p[e] *= inv;
    int i0 = 0;
#pragma unroll
    for (int e = 1; e < 8; ++e) if (p[e] > p[i0]) i0 = e;
    int i1 = (i0 == 0) ? 1 : 0;
#pragma unroll
    for (int e = 0; e < 8; ++e) if (e != i0 && p[e] > p[i1]) i1 = e;
#pragma unroll
    for (int e = 0; e < 8; ++e) probs_lds[tl][e] = p[e];
    topi_lds[tl][0] = i0; topi_lds[tl][1] = i1;
    int s0 = atomicAdd(&counts[i0], 1);
    entry_token[i0 * T_TOK + s0] = token;
    entry_gate[i0 * T_TOK + s0] = p[i0];
    ids[token * 2] = i0; slots[token * 2] = s0;
    int s1 = atomicAdd(&counts[i1], 1);
    entry_token[i1 * T_TOK + s1] = token;
    entry_gate[i1 * T_TOK + s1] = p[i1];
    ids[token * 2 + 1] = i1; slots[token * 2 + 1] = s1;
  }
  __syncthreads();
  if (tid < 24) {
    int e = tid & 7, which = tid >> 3;
    float s = 0.f;
#pragma unroll
    for (int tt = 0; tt < 4; ++tt) {
      float pv = probs_lds[tt][e];
      bool m = (topi_lds[tt][0] == e) || (topi_lds[tt][1] == e);
      if (which == 0) s += pv;
      else if (which == 1) s += m ? 1.f : 0.f;
      else s += m ? pv : 0.f;
    }
    partials[blockIdx.x * 24 + tid] = s;
  }
}

// ---------------- offsets (pad 256) + 256-row tile map ----------------
__global__ void offsets_kernel(const int* __restrict__ counts, int* __restrict__ hoff,
                               int* __restrict__ tmap) {
  if (threadIdx.x == 0 && blockIdx.x == 0) {
    int o = 0, nt = 0;
    for (int e = 0; e < E_EXP; ++e) {
      hoff[e] = o;
      int rtc = (counts[e] + 255) >> 8;
      o += rtc << 8;
      for (int rt = 0; rt < rtc; ++rt) tmap[nt++] = (e << 16) | rt;
    }
    hoff[E_EXP] = o;
    for (; nt < NT; ++nt) tmap[nt] = -1;
  }
}

// ---------------- aux loss ----------------
__global__ void aux_kernel(const float* __restrict__ partials, float* __restrict__ out_aux) {
  __shared__ float red[24][33];
  const int tid = threadIdx.x;              // 1024 threads
  const int c = tid & 31, g = tid >> 5;
  if (c < 24) {
    float s = 0.f;
    for (int j = 0; j < 32; ++j) s += partials[(size_t)(g + j * 32) * 24 + c];
    red[c][g] = s;
  }
  __syncthreads();
  if (tid < 24) {
    float t2 = 0.f;
#pragma unroll
    for (int g2 = 0; g2 < 32; ++g2) t2 += red[tid][g2];
    red[tid][32] = t2;
  }
  __syncthreads();
  if (tid == 0) {
    float mean = 0.f;
    for (int e = 0; e < 8; ++e) mean += red[e][32];
    mean *= 0.125f;
    float var = 0.f;
    for (int e = 0; e < 8; ++e) { float d = red[e][32] - mean; var += d * d; }
    var *= (1.f / 7.f);
    float il = var * (1.f / 64.f);
    float lb = 0.f;
    for (int e = 0; e < 8; ++e)
      lb += (red[8 + e][32] / (float)T_TOK) * (red[16 + e][32] / (float)T_TOK);
    lb *= 8.f;
    out_aux[0] = il + lb;
  }
}

// ======== 256x256x64 8-phase grouped-GEMM machinery ========
// LDS: sA [2 dbuf][2 half][16KB st_16x32-swizzled], sB same; 128KB total.
// Staged via global_load_lds (linear dest) with pre-swizzled global source.
// Per-thread chunk params: thread t stages rows r0 and r0+64 of a half,
// k-bytes at kb (swizzle folded in).
#define STG_A0(m_) { char* lb_ = sA + ((m_)&1)*32768 + wv*1024; \
  load_lds16(pa0s0 + (size_t)(m_)*128, lb_); load_lds16(pa0s1 + (size_t)(m_)*128, lb_ + 8192); }
#define STG_A1(m_) { char* lb_ = sA + ((m_)&1)*32768 + 16384 + wv*1024; \
  load_lds16(pa1s0 + (size_t)(m_)*128, lb_); load_lds16(pa1s1 + (size_t)(m_)*128, lb_ + 8192); }
#define STG_B0(m_) { char* lb_ = sB + ((m_)&1)*32768 + wv*1024; \
  load_lds16(pb0s0 + (size_t)(m_)*128, lb_); load_lds16(pb0s1 + (size_t)(m_)*128, lb_ + 8192); }
#define STG_B1(m_) { char* lb_ = sB + ((m_)&1)*32768 + 16384 + wv*1024; \
  load_lds16(pb1s0 + (size_t)(m_)*128, lb_); load_lds16(pb1s1 + (size_t)(m_)*128, lb_ + 8192); }

#define LDA(DST, MB) \
  _Pragma("unroll") for (int mi = 0; mi < 4; ++mi) \
  _Pragma("unroll") for (int kk = 0; kk < 2; ++kk) \
    DST[mi][kk] = *(const bf16x8*)(Ad + ((MB) + mi) * 2048 + kk * 1024 + lane_off);
#define LDB(DST, CB) \
  _Pragma("unroll") for (int ni = 0; ni < 2; ++ni) \
  _Pragma("unroll") for (int kk = 0; kk < 2; ++kk) \
    DST[ni][kk] = *(const bf16x8*)(Bd + ((CB) + ni) * 2048 + kk * 1024 + lane_off);
#define MFMA16(AF, BF, MB, NB) \
  _Pragma("unroll") for (int mi = 0; mi < 4; ++mi) \
  _Pragma("unroll") for (int ni = 0; ni < 2; ++ni) \
  _Pragma("unroll") for (int kk = 0; kk < 2; ++kk) \
    acc[(MB)+mi][(NB)+ni] = __builtin_amdgcn_mfma_f32_16x16x32_bf16(AF[mi][kk], BF[ni][kk], acc[(MB)+mi][(NB)+ni], 0, 0, 0);

#define KLOOP_BODY(KT) \
  for (int k = 0; k < (KT); ++k) { \
    const char* Ad = sA + (k & 1) * 32768 + halfA * 16384; \
    const char* Bd = sB + (k & 1) * 32768 + halfB * 16384; \
    bf16x8 alo[4][2], blo[2][2], ahi[4][2], bhi[2][2]; \
    LDA(alo, 0); LDB(blo, cg0); \
    if (k + 1 < (KT)) STG_A1(k + 1); \
    BAR(); \
    __builtin_amdgcn_s_setprio(1); MFMA16(alo, blo, 0, 0); __builtin_amdgcn_s_setprio(0); \
    BAR(); \
    LDB(bhi, cg0 + 2); \
    if (k + 1 < (KT)) STG_B0(k + 1); \
    BAR(); \
    __builtin_amdgcn_s_setprio(1); MFMA16(alo, bhi, 0, 2); __builtin_amdgcn_s_setprio(0); \
    BAR(); \
    LDA(ahi, 4); \
    if (k + 1 < (KT)) STG_B1(k + 1); \
    BAR(); \
    __builtin_amdgcn_s_setprio(1); MFMA16(ahi, blo, 4, 0); __builtin_amdgcn_s_setprio(0); \
    BAR(); \
    if (k + 2 < (KT)) STG_A0(k + 2); \
    BAR(); \
    __builtin_amdgcn_s_setprio(1); MFMA16(ahi, bhi, 4, 2); __builtin_amdgcn_s_setprio(0); \
    if (k + 2 < (KT)) { VM2(); } else { VM0(); } \
    BAR(); \
  }

// ---------------- GEMM1: h = relu(gather(xb) @ w1t[e]^T + b1[e]) ----------------
__global__ __launch_bounds__(512, 2) void gemm1_kernel(
    const unsigned short* __restrict__ xb,    // [T][1024]
    const unsigned short* __restrict__ w1t,   // [E][4096][1024] (N-major)
    const float* __restrict__ b1,
    const int* __restrict__ counts, const int* __restrict__ hoff,
    const int* __restrict__ tmap, const int* __restrict__ entry_token,
    unsigned short* __restrict__ h)           // [HROWS][4096]
{
  extern __shared__ char smem[];
  char* sA = smem;
  char* sB = smem + 65536;
  int* tok = (int*)(smem + 131072);
  int lin = blockIdx.x * NT + blockIdx.y;       // ct-major: B-tile reuse within XCD chunk
  lin = (lin & 7) * (16 * NT / 8) + (lin >> 3); // bijective XCD swizzle, nwg=640
  const int ti = lin % NT, ct = lin / NT;
  const int mEnc = tmap[ti];
  if (mEnc < 0) return;
  const int e = mEnc >> 16, rt = mEnc & 0xffff;
  const int cnt = counts[e];
  const int tid = threadIdx.x, lane = tid & 63, wv = tid >> 6;
  if (tid < 256) {
    int s = rt * 256 + tid;
    if (s >= cnt) s = cnt - 1;
    tok[tid] = entry_token[e * T_TOK + s];
  }
  __syncthreads();
  // stage-side chunk decomposition (st_16x32: pre-swizzled global source)
  const int r0 = ((tid >> 7) << 4) + ((tid >> 2) & 15);                       // [0,64)
  const int kb = (((tid >> 6) & 1) << 5) + (((tid & 3) << 3) ^ (((tid >> 5) & 1) << 4));
  const char* xbb = (const char*)xb;
  const char* pa0s0 = xbb + (size_t)tok[r0]       * 2048 + kb * 2;
  const char* pa0s1 = xbb + (size_t)tok[64 + r0]  * 2048 + kb * 2;
  const char* pa1s0 = xbb + (size_t)tok[128 + r0] * 2048 + kb * 2;
  const char* pa1s1 = xbb + (size_t)tok[192 + r0] * 2048 + kb * 2;
  const char* w1e = (const char*)w1t + ((size_t)e * DFF_D + ct * 256) * (H_DIM * 2);
  const char* pb0s0 = w1e + (size_t)(r0)       * 2048 + kb * 2;
  const char* pb0s1 = w1e + (size_t)(64 + r0)  * 2048 + kb * 2;
  const char* pb1s0 = w1e + (size_t)(128 + r0) * 2048 + kb * 2;
  const char* pb1s1 = w1e + (size_t)(192 + r0) * 2048 + kb * 2;
  // read-side
  const int halfA = wv >> 2, halfB = (wv & 3) >> 1, cg0 = (wv & 1) * 4;
  const int wm = (wv >> 2) * 128, wn = (wv & 3) * 64;
  const int lane_off = (lane & 15) * 64 + ((((lane >> 4) << 3) ^ (((lane >> 3) & 1) << 4)) << 1);
  f32x4 acc[8][4];
#pragma unroll
  for (int mi = 0; mi < 8; ++mi)
#pragma unroll
    for (int ni = 0; ni < 4; ++ni) acc[mi][ni] = (f32x4){0.f, 0.f, 0.f, 0.f};
  // prologue: 5 half-tiles ahead
  STG_A0(0); STG_A1(0); STG_B0(0); STG_B1(0); STG_A0(1);
  VM2();
  BAR();
  KLOOP_BODY(16)
  // epilogue
  const int rb = hoff[e] + rt * 256;
#pragma unroll
  for (int mi = 0; mi < 8; ++mi)
#pragma unroll
    for (int ni = 0; ni < 4; ++ni) {
      const int n = ct * 256 + wn + ni * 16 + (lane & 15);
      const float bias = b1[e * DFF_D + n];
#pragma unroll
      for (int q = 0; q < 4; ++q) {
        const int m = wm + mi * 16 + (lane >> 4) * 4 + q;
        float v = acc[mi][ni][q] + bias;
        v = v > 0.f ? v : 0.f;
        h[(size_t)(rb + m) * DFF_D + n] = f2bf(v);
      }
    }
}

// ---------------- GEMM2: yp[part] = gate * (h @ w2t[e]^T (+ b2)) , split-K=3 ----------------
__global__ __launch_bounds__(512, 2) void gemm2_kernel(
    const unsigned short* __restrict__ h,     // [HROWS][4096]
    const unsigned short* __restrict__ w2t,   // [E][1024][4096] (N-major)
    const float* __restrict__ b2,
    const int* __restrict__ hoff, const int* __restrict__ tmap,
    const float* __restrict__ entry_gate,
    unsigned short* __restrict__ yp)          // [3][HROWS][1024]
{
  extern __shared__ char smem[];
  char* sA = smem;
  char* sB = smem + 65536;
  int lin = (blockIdx.z * NT + blockIdx.y) * 4 + blockIdx.x;  // (part,ti)-major: A reuse
  lin = (lin & 7) * (3 * NT * 4 / 8) + (lin >> 3);            // bijective, nwg=480
  const int ct = lin & 3;
  const int g = lin >> 2;
  const int ti = g % NT, part = g / NT;
  const int mEnc = tmap[ti];
  if (mEnc < 0) return;
  const int e = mEnc >> 16, rt = mEnc & 0xffff;
  int S, KT;
  if (part == 0)      { S = 0;  KT = 22; }
  else if (part == 1) { S = 22; KT = 21; }
  else                { S = 43; KT = 21; }
  const int tid = threadIdx.x, lane = tid & 63, wv = tid >> 6;
  const int rb = hoff[e] + rt * 256;
  const int r0 = ((tid >> 7) << 4) + ((tid >> 2) & 15);
  const int kb = (((tid >> 6) & 1) << 5) + (((tid & 3) << 3) ^ (((tid >> 5) & 1) << 4));
  const char* hb = (const char*)h + (size_t)S * 128;
  const char* pa0s0 = hb + (size_t)(rb + r0)       * 8192 + kb * 2;
  const char* pa0s1 = hb + (size_t)(rb + 64 + r0)  * 8192 + kb * 2;
  const char* pa1s0 = hb + (size_t)(rb + 128 + r0) * 8192 + kb * 2;
  const char* pa1s1 = hb + (size_t)(rb + 192 + r0) * 8192 + kb * 2;
  const char* w2e = (const char*)w2t + ((size_t)e * H_DIM + ct * 256) * (DFF_D * 2) + (size_t)S * 128;
  const char* pb0s0 = w2e + (size_t)(r0)       * 8192 + kb * 2;
  const char* pb0s1 = w2e + (size_t)(64 + r0)  * 8192 + kb * 2;
  const char* pb1s0 = w2e + (size_t)(128 + r0) * 8192 + kb * 2;
  const char* pb1s1 = w2e + (size_t)(192 + r0) * 8192 + kb * 2;
  const int halfA = wv >> 2, halfB = (wv & 3) >> 1, cg0 = (wv & 1) * 4;
  const int wm = (wv >> 2) * 128, wn = (wv & 3) * 64;
  const int lane_off = (lane & 15) * 64 + ((((lane >> 4) << 3) ^ (((lane >> 3) & 1) << 4)) << 1);
  f32x4 acc[8][4];
#pragma unroll
  for (int mi = 0; mi < 8; ++mi)
#pragma unroll
    for (int ni = 0; ni < 4; ++ni) acc[mi][ni] = (f32x4){0.f, 0.f, 0.f, 0.f};
  STG_A0(0); STG_A1(0); STG_B0(0); STG_B1(0); STG_A0(1);
  VM2();
  BAR();
  KLOOP_BODY(KT)
  unsigned short* yout = yp + (size_t)part * HROWS * H_DIM;
#pragma unroll
  for (int mi = 0; mi < 8; ++mi)
#pragma unroll
    for (int ni = 0; ni < 4; ++ni) {
      const int n = ct * 256 + wn + ni * 16 + (lane & 15);
      const float bias = (part == 0) ? b2[e * H_DIM + n] : 0.f;
#pragma unroll
      for (int q = 0; q < 4; ++q) {
        const int m = wm + mi * 16 + (lane >> 4) * 4 + q;
        const float gate = entry_gate[e * T_TOK + rt * 256 + m]; // garbage on pad rows: never read
        float v = (acc[mi][ni][q] + bias) * gate;
        yout[(size_t)(rb + m) * H_DIM + n] = f2bf(v);
      }
    }
}

// ---------------- combine: out[t] = sum_{p,k} yp[p][row(t,k)] ----------------
__global__ void combine_kernel(const unsigned short* __restrict__ yp,
                               const int* __restrict__ ids, const int* __restrict__ slots,
                               const int* __restrict__ hoff, float* __restrict__ out) {
  const int t = blockIdx.x, tid = threadIdx.x;
  const int r0 = hoff[ids[t * 2]] + slots[t * 2];
  const int r1 = hoff[ids[t * 2 + 1]] + slots[t * 2 + 1];
  const int c = tid * 4;
  float4 o = {0.f, 0.f, 0.f, 0.f};
#pragma unroll
  for (int p = 0; p < 3; ++p) {
    const unsigned short* pl = yp + (size_t)p * HROWS * H_DIM;
    ushort4 a = *(const ushort4*)&pl[(size_t)r0 * H_DIM + c];
    ushort4 b = *(const ushort4*)&pl[(size_t)r1 * H_DIM + c];
    o.x += bf2f(a.x) + bf2f(b.x);
    o.y += bf2f(a.y) + bf2f(b.y);
    o.z += bf2f(a.z) + bf2f(b.z);
    o.w += bf2f(a.w) + bf2f(b.w);
  }
  *(float4*)&out[(size_t)t * H_DIM + c] = o;
}

__global__ void ws_fail_kernel(float* out) {
  if (threadIdx.x == 0 && blockIdx.x == 0) out[0] = -12345.0f;
}

// ---------------- workspace layout (bytes) ----------------
#define XB_OFF    ((size_t)0)           // 8,388,608   (dead after gemm1)
#define W1T_OFF   ((size_t)8388608)     // 67,108,864  (dead after gemm1)
#define YP_OFF    ((size_t)0)           // 3*10240*1024*2 = 62,914,560 (aliases xb+w1t)
#define W2T_OFF   ((size_t)75497472)    // 67,108,864
#define H_OFF     ((size_t)142606336)   // 83,886,080
#define TMAP_OFF  ((size_t)226492416)   // 256
#define ET_OFF    ((size_t)226492672)   // 131,072
#define EG_OFF    ((size_t)226623744)   // 131,072
#define IDS_OFF   ((size_t)226754816)   // 32,768
#define SLOT_OFF  ((size_t)226787584)   // 32,768
#define CNT_OFF   ((size_t)226820352)   // 64
#define HOFF_OFF  ((size_t)226820416)   // 64
#define PART_OFF  ((size_t)226820480)   // 98,304
#define WS_NEED   ((size_t)226918784)

extern "C" void kernel_launch(void* const* d_in, const int* in_sizes, int n_in,
                              void* d_out, int out_size, void* d_ws, size_t ws_size,
                              hipStream_t stream) {
  const float* x  = (const float*)d_in[0];
  const float* gw = (const float*)d_in[1];
  const float* gb = (const float*)d_in[2];
  const float* w1 = (const float*)d_in[3];
  const float* b1 = (const float*)d_in[4];
  const float* w2 = (const float*)d_in[5];
  const float* b2 = (const float*)d_in[6];
  float* out = (float*)d_out;
  char* ws = (char*)d_ws;

  if (ws_size < WS_NEED) {
    ws_fail_kernel<<<1, 64, 0, stream>>>(out);
    return;
  }

  unsigned short* xb  = (unsigned short*)(ws + XB_OFF);
  unsigned short* w1t = (unsigned short*)(ws + W1T_OFF);
  unsigned short* yp  = (unsigned short*)(ws + YP_OFF);
  unsigned short* w2t = (unsigned short*)(ws + W2T_OFF);
  unsigned short* h   = (unsigned short*)(ws + H_OFF);
  int*   tmap  = (int*)(ws + TMAP_OFF);
  int*   etok  = (int*)(ws + ET_OFF);
  float* egate = (float*)(ws + EG_OFF);
  int*   ids   = (int*)(ws + IDS_OFF);
  int*   slots = (int*)(ws + SLOT_OFF);
  int*   counts= (int*)(ws + CNT_OFF);
  int*   hoff  = (int*)(ws + HOFF_OFF);
  float* parts = (float*)(ws + PART_OFF);

  hipMemsetAsync(counts, 0, 32, stream);

  cvt_x_kernel<<<2048, 256, 0, stream>>>(x, xb);
  tr_cvt_kernel<<<dim3(64, 16, 8), 256, 0, stream>>>(w1, w1t, H_DIM, DFF_D);
  tr_cvt_kernel<<<dim3(16, 64, 8), 256, 0, stream>>>(w2, w2t, DFF_D, H_DIM);
  gate_kernel<<<1024, 256, 0, stream>>>(x, gw, gb, counts, etok, egate, ids, slots, parts);
  offsets_kernel<<<1, 64, 0, stream>>>(counts, hoff, tmap);
  aux_kernel<<<1, 1024, 0, stream>>>(parts, out + (size_t)T_TOK * H_DIM);
  gemm1_kernel<<<dim3(16, NT), 512, 132096, stream>>>(xb, w1t, b1, counts, hoff, tmap, etok, h);
  gemm2_kernel<<<dim3(4, NT, 3), 512, 131072, stream>>>(h, w2t, b2, hoff, tmap, egate, yp);
  combine_kernel<<<4096, 256, 0, stream>>>(yp, ids, slots, hoff, out);
}